// Round 1
// baseline (45.549 us; speedup 1.0000x reference)
//
#include <hip/hip_runtime.h>

// BoundNoiseSampler weight: out = karras_weight + 2*new_weight
//   karras = 4 + 1/sig2
//   inv_C  = exp(-196/sig2) / (6*(196+sig2))   [== where(isfinite(C), 1/C, 0)]
//   integral = 0.5 * sig2 * inv_C
//   new_weight = 0.5/sig2 * exp(-integral)
//   out = 4 + (1/sig2) * (1 + exp(-integral))
// Memory-bound elementwise: float4 loads/stores, grid-stride, 2048 blocks.

__device__ __forceinline__ float bns_elem(float sig) {
    const float FOUR_R2 = 196.0f;              // 4*R^2, R=7
    float sig2     = sig * sig;
    float inv_sig2 = __builtin_amdgcn_rcpf(sig2);
    // exp(-196/sig2): goes to 0 as sig->0, which makes inv_C -> 0 exactly
    // like the reference's isfinite() guard, branch-free.
    float e_neg    = __expf(-FOUR_R2 * inv_sig2);
    float inv_den  = __builtin_amdgcn_rcpf(6.0f * (FOUR_R2 + sig2));
    float inv_C    = e_neg * inv_den;
    float integral = 0.5f * sig2 * inv_C;
    float w        = __expf(-integral);
    return 4.0f + inv_sig2 * (1.0f + w);
}

__global__ void __launch_bounds__(256)
bns_kernel_vec4(const float* __restrict__ sigma, float* __restrict__ out, int nvec) {
    const float4* in4  = reinterpret_cast<const float4*>(sigma);
    float4*       out4 = reinterpret_cast<float4*>(out);
    int idx    = blockIdx.x * blockDim.x + threadIdx.x;
    int stride = gridDim.x * blockDim.x;
    for (int i = idx; i < nvec; i += stride) {
        float4 s = in4[i];
        float4 r;
        r.x = bns_elem(s.x);
        r.y = bns_elem(s.y);
        r.z = bns_elem(s.z);
        r.w = bns_elem(s.w);
        out4[i] = r;
    }
}

__global__ void __launch_bounds__(64)
bns_kernel_tail(const float* __restrict__ sigma, float* __restrict__ out,
                int start, int n) {
    int i = start + blockIdx.x * blockDim.x + threadIdx.x;
    if (i < n) out[i] = bns_elem(sigma[i]);
}

extern "C" void kernel_launch(void* const* d_in, const int* in_sizes, int n_in,
                              void* d_out, int out_size, void* d_ws, size_t ws_size,
                              hipStream_t stream) {
    const float* sigma = (const float*)d_in[0];
    float*       out   = (float*)d_out;
    int n    = in_sizes[0];
    int nvec = n >> 2;                 // float4 elements
    int rem  = n - (nvec << 2);

    if (nvec > 0) {
        int blocks = (nvec + 255) / 256;
        if (blocks > 2048) blocks = 2048;
        bns_kernel_vec4<<<blocks, 256, 0, stream>>>(sigma, out, nvec);
    }
    if (rem > 0) {
        bns_kernel_tail<<<1, 64, 0, stream>>>(sigma, out, nvec << 2, n);
    }
}

// Round 3
// 44.461 us; speedup vs baseline: 1.0245x; 1.0245x over previous
//
#include <hip/hip_runtime.h>

// BoundNoiseSampler weight: out = 4 + (1/sig2) * (1 + exp(-integral))
//   inv_C    = exp(-196/sig2) / (6*(196+sig2))   [== where(isfinite(C), 1/C, 0)]
//   integral = 0.5 * sig2 * inv_C
// Memory-bound elementwise. float4 loads, NON-TEMPORAL float4 stores
// (keep the 128MB write stream out of L3 so sigma stays L3-resident
// across graph replays), grid-stride with 4096 blocks.
// NOTE: __builtin_nontemporal_store requires a NATIVE vector type, not
// HIP_vector_type<float,4> — use ext_vector_type(4).

typedef float v4f __attribute__((ext_vector_type(4)));

__device__ __forceinline__ float bns_elem(float sig) {
    const float FOUR_R2 = 196.0f;              // 4*R^2, R=7
    float sig2     = sig * sig;
    float inv_sig2 = __builtin_amdgcn_rcpf(sig2);
    float e_neg    = __expf(-FOUR_R2 * inv_sig2);   // ->0 as sig->0 (matches isfinite guard)
    float inv_den  = __builtin_amdgcn_rcpf(6.0f * (FOUR_R2 + sig2));
    float inv_C    = e_neg * inv_den;
    float integral = 0.5f * sig2 * inv_C;
    float w        = __expf(-integral);
    return 4.0f + inv_sig2 * (1.0f + w);
}

__global__ void __launch_bounds__(256)
bns_kernel_vec4(const float* __restrict__ sigma, float* __restrict__ out, int nvec) {
    const v4f* in4  = reinterpret_cast<const v4f*>(sigma);
    v4f*       out4 = reinterpret_cast<v4f*>(out);
    int idx    = blockIdx.x * blockDim.x + threadIdx.x;
    int stride = gridDim.x * blockDim.x;
    for (int i = idx; i < nvec; i += stride) {
        v4f s = in4[i];
        v4f r;
        r.x = bns_elem(s.x);
        r.y = bns_elem(s.y);
        r.z = bns_elem(s.z);
        r.w = bns_elem(s.w);
        __builtin_nontemporal_store(r, &out4[i]);
    }
}

__global__ void __launch_bounds__(64)
bns_kernel_tail(const float* __restrict__ sigma, float* __restrict__ out,
                int start, int n) {
    int i = start + blockIdx.x * blockDim.x + threadIdx.x;
    if (i < n) out[i] = bns_elem(sigma[i]);
}

extern "C" void kernel_launch(void* const* d_in, const int* in_sizes, int n_in,
                              void* d_out, int out_size, void* d_ws, size_t ws_size,
                              hipStream_t stream) {
    const float* sigma = (const float*)d_in[0];
    float*       out   = (float*)d_out;
    int n    = in_sizes[0];
    int nvec = n >> 2;                 // float4 elements
    int rem  = n - (nvec << 2);

    if (nvec > 0) {
        int blocks = (nvec + 255) / 256;
        if (blocks > 4096) blocks = 4096;
        bns_kernel_vec4<<<blocks, 256, 0, stream>>>(sigma, out, nvec);
    }
    if (rem > 0) {
        bns_kernel_tail<<<1, 64, 0, stream>>>(sigma, out, nvec << 2, n);
    }
}